// Round 2
// baseline (1401.945 us; speedup 1.0000x reference)
//
#include <hip/hip_runtime.h>
#include <math.h>

// ---- problem constants ----
#define TOK    50176      // 2*8*56*56 tokens
#define CH     128
#define NWIN   128        // B * 64 windows
#define NTOK   392        // 8*7*7 tokens per window
#define NHEADS 4
#define HD     32
#define QSCALE 0.17677669529663687f   // 32^-0.5
#define LNEPS  1e-3f

// ---- bf16 <-> f32 helpers for LDS staging only ----
__device__ __forceinline__ float bf2f(unsigned short u) {
    return __uint_as_float(((unsigned)u) << 16);
}
__device__ __forceinline__ unsigned short f2bf(float f) {
    unsigned u = __float_as_uint(f);
    unsigned r = (u + 0x7fffu + ((u >> 16) & 1u)) >> 16;
    return (unsigned short)r;
}

// token m in window layout (b=m/392, t=m%392) -> flat token index in original
// (batch,d,h,w) layout, with the +3 roll applied (same map for shift-gather
// and unshift-scatter).
__device__ __forceinline__ int src_index(int m) {
    int b = m / NTOK, t = m - b * NTOK;
    int batch = b >> 6, wIdx = b & 63;
    int bh = wIdx >> 3, bw = wIdx & 7;
    int d = t / 49, rem = t - d * 49;
    int h7 = rem / 7, w7 = rem - h7 * 7;
    int h = bh * 7 + h7 + 3; if (h >= 56) h -= 56;
    int w = bw * 7 + w7 + 3; if (w >= 56) w -= 56;
    return ((batch * 8 + d) * 56 + h) * 56 + w;
}

// ---- LayerNorm kernels ----
// MODE 0: gather f32 x via src_index (LN1 + shift + window_partition), out fp32 window layout
// MODE 1: read fp32 buffer directly (LN2)
template<int MODE>
__global__ __launch_bounds__(128) void ln_kernel(
    const float* __restrict__ xin,
    const float* __restrict__ g, const float* __restrict__ bta,
    float* __restrict__ out)
{
    int m = blockIdx.x, c = threadIdx.x;
    float v;
    if (MODE == 0) {
        int src = src_index(m);
        v = xin[(size_t)src * CH + c];
    } else {
        v = xin[(size_t)m * CH + c];
    }
    float s1 = v, s2 = v * v;
    #pragma unroll
    for (int o = 32; o; o >>= 1) { s1 += __shfl_xor(s1, o); s2 += __shfl_xor(s2, o); }
    __shared__ float ps[2][2];
    int w = c >> 6;
    if ((c & 63) == 0) { ps[w][0] = s1; ps[w][1] = s2; }
    __syncthreads();
    s1 = ps[0][0] + ps[1][0];
    s2 = ps[0][1] + ps[1][1];
    float mean = s1 * (1.f / CH);
    float var  = s2 * (1.f / CH) - mean * mean;
    float r = rsqrtf(var + LNEPS);
    out[(size_t)m * CH + c] = (v - mean) * r * g[c] + bta[c];
}

// ---- generic tiled GEMM: C = A(MxK fp32) * B(KxN fp32) + bias, with epilogues ----
// EPI 1: qkv  (scale cols < 128 by QSCALE)
// EPI 2: proj (residual scatter): R[dst] = x[dst] + v, dst via src_index
// EPI 3: gelu (exact erf)
// EPI 4: fc2 + residual -> f32 d_out
template<int EPI>
__global__ __launch_bounds__(256) void gemm_k(
    const float* __restrict__ A, const float* __restrict__ B,
    const float* __restrict__ bias, float* __restrict__ Cout,
    int M, int Nn, int K,
    const float* __restrict__ resid)
{
    __shared__ float As[16][66];   // [k][m], padded
    __shared__ float Bs[16][64];   // [k][n]
    int tid = threadIdx.x;
    int tx = tid & 15, ty = tid >> 4;
    int m0 = blockIdx.y * 64, n0 = blockIdx.x * 64;
    float acc[4][4] = {};
    for (int k0 = 0; k0 < K; k0 += 16) {
        #pragma unroll
        for (int p = 0; p < 4; ++p) {
            int e = tid + p * 256;        // over (row, k)
            int r = e >> 4, kk = e & 15;
            As[kk][r] = A[(size_t)(m0 + r) * K + k0 + kk];
        }
        #pragma unroll
        for (int p = 0; p < 4; ++p) {
            int e = tid + p * 256;        // over (k, n)
            int kk = e >> 6, n = e & 63;
            Bs[kk][n] = B[(size_t)(k0 + kk) * Nn + n0 + n];
        }
        __syncthreads();
        #pragma unroll
        for (int kk = 0; kk < 16; ++kk) {
            float a[4], b[4];
            #pragma unroll
            for (int i = 0; i < 4; ++i) a[i] = As[kk][ty * 4 + i];
            #pragma unroll
            for (int j = 0; j < 4; ++j) b[j] = Bs[kk][tx * 4 + j];
            #pragma unroll
            for (int i = 0; i < 4; ++i)
                #pragma unroll
                for (int j = 0; j < 4; ++j)
                    acc[i][j] = fmaf(a[i], b[j], acc[i][j]);
        }
        __syncthreads();
    }
    #pragma unroll
    for (int i = 0; i < 4; ++i) {
        int m = m0 + ty * 4 + i;
        #pragma unroll
        for (int j = 0; j < 4; ++j) {
            int n = n0 + tx * 4 + j;
            float v = acc[i][j] + bias[n];
            if (EPI == 1) {
                if (n < 128) v *= QSCALE;
                Cout[(size_t)m * Nn + n] = v;
            } else if (EPI == 2) {
                int dst = src_index(m);
                Cout[(size_t)dst * CH + n] = v + resid[(size_t)dst * CH + n];
            } else if (EPI == 3) {
                Cout[(size_t)m * Nn + n] = 0.5f * v * (1.f + erff(v * 0.70710678118654752f));
            } else { // EPI == 4
                Cout[(size_t)m * CH + n] = v + resid[(size_t)m * CH + n];
            }
        }
    }
}

// ---- attention: one block per (window b, head, group of 8 query rows) ----
// grid = (49, 4, 128), block = 256 (8 rows x 32 lanes)
__global__ __launch_bounds__(256) void attn_k(
    const float* __restrict__ Q, const float* __restrict__ rpb,
    float* __restrict__ O)
{
    __shared__ unsigned short k_lds[NTOK][33];  // bf16-staged, pad 33
    __shared__ unsigned short v_lds[NTOK][33];
    __shared__ float p_lds[8][NTOK];
    __shared__ float q_lds[8][32];

    int b = blockIdx.z, head = blockIdx.y, rg = blockIdx.x;
    int tid = threadIdx.x;
    int r = tid >> 5, l = tid & 31;
    const size_t qbase = (size_t)b * NTOK * 384;

    for (int e = tid; e < NTOK * 32; e += 256) {
        int j = e >> 5, d = e & 31;
        size_t rowb = qbase + (size_t)j * 384 + head * 32 + d;
        k_lds[j][d] = f2bf(Q[rowb + 128]);
        v_lds[j][d] = f2bf(Q[rowb + 256]);
    }
    {
        int jr = tid >> 5, d = tid & 31;
        int i = rg * 8 + jr;
        q_lds[jr][d] = Q[qbase + (size_t)i * 384 + head * 32 + d];
    }
    __syncthreads();

    int i = rg * 8 + r;
    int di = i / 49, remi = i - di * 49, hi = remi / 7, wi = remi - hi * 7;
    int wIdx = b & 63, bh = wIdx >> 3, bw = wIdx & 7;
    int Hi = bh * 7 + hi, Wi = bw * 7 + wi;
    int regi = (Hi < 49 ? 0 : (Hi < 53 ? 1 : 2)) * 3 + (Wi < 49 ? 0 : (Wi < 53 ? 1 : 2));

    float smax = -1e30f;
    for (int j = l; j < NTOK; j += 32) {
        float s = 0.f;
        #pragma unroll
        for (int d = 0; d < 32; ++d)
            s = fmaf(q_lds[r][d], bf2f(k_lds[j][d]), s);
        int dj = j / 49, remj = j - dj * 49, hj = remj / 7, wj = remj - hj * 7;
        int bidx = (di - dj + 7) * 169 + (hi - hj + 6) * 13 + (wi - wj + 6);
        s += rpb[bidx * NHEADS + head];
        int Hj = bh * 7 + hj, Wj = bw * 7 + wj;
        int regj = (Hj < 49 ? 0 : (Hj < 53 ? 1 : 2)) * 3 + (Wj < 49 ? 0 : (Wj < 53 ? 1 : 2));
        if (regj != regi) s -= 100.f;
        p_lds[r][j] = s;
        smax = fmaxf(smax, s);
    }
    #pragma unroll
    for (int o = 16; o; o >>= 1) smax = fmaxf(smax, __shfl_xor(smax, o, 32));

    float ssum = 0.f;
    for (int j = l; j < NTOK; j += 32) {
        float p = expf(p_lds[r][j] - smax);
        p_lds[r][j] = p;
        ssum += p;
    }
    #pragma unroll
    for (int o = 16; o; o >>= 1) ssum += __shfl_xor(ssum, o, 32);
    __syncthreads();

    float acc = 0.f;
    #pragma unroll 8
    for (int j = 0; j < NTOK; ++j)
        acc = fmaf(p_lds[r][j], bf2f(v_lds[j][l]), acc);

    O[(size_t)(b * NTOK + i) * CH + head * 32 + l] = acc / ssum;
}

extern "C" void kernel_launch(void* const* d_in, const int* in_sizes, int n_in,
                              void* d_out, int out_size, void* d_ws, size_t ws_size,
                              hipStream_t stream) {
    const float* x      = (const float*)d_in[0];
    const float* n1g    = (const float*)d_in[1];
    const float* n1b    = (const float*)d_in[2];
    const float* qkv_w  = (const float*)d_in[3];
    const float* qkv_b  = (const float*)d_in[4];
    const float* proj_w = (const float*)d_in[5];
    const float* proj_b = (const float*)d_in[6];
    const float* rpb    = (const float*)d_in[7];
    const float* n2g    = (const float*)d_in[8];
    const float* n2b    = (const float*)d_in[9];
    const float* fc1_w  = (const float*)d_in[10];
    const float* fc1_b  = (const float*)d_in[11];
    const float* fc2_w  = (const float*)d_in[12];
    const float* fc2_b  = (const float*)d_in[13];
    float* out = (float*)d_out;

    char* ws = (char*)d_ws;
    const size_t SA = (size_t)TOK * CH * sizeof(float);  // 25.69 MB
    float* A  = (float*)(ws);            // LN out                   (SA)
    float* R  = (float*)(ws + SA);       // residual x + attn        (SA)
    float* Qb = (float*)(ws + 2 * SA);   // qkv                      (3*SA)
    float* O  = (float*)(ws + 5 * SA);   // attn out                 (SA)
    float* H  = (float*)(ws + 2 * SA);   // gelu(fc1) overlays Qb+O  (4*SA)

    // 1. LN1 + shift + window_partition
    hipLaunchKernelGGL((ln_kernel<0>), dim3(TOK), dim3(128), 0, stream,
                       x, n1g, n1b, A);
    // 2. qkv GEMM (+bias, q-scale)
    hipLaunchKernelGGL((gemm_k<1>), dim3(384 / 64, TOK / 64), dim3(256), 0, stream,
                       A, qkv_w, qkv_b, Qb, TOK, 384, 128, nullptr);
    // 3. windowed attention
    hipLaunchKernelGGL(attn_k, dim3(NTOK / 8, NHEADS, NWIN), dim3(256), 0, stream,
                       Qb, rpb, O);
    // 4. proj GEMM + window_reverse + unshift + residual add -> R
    hipLaunchKernelGGL((gemm_k<2>), dim3(128 / 64, TOK / 64), dim3(256), 0, stream,
                       O, proj_w, proj_b, R, TOK, 128, 128, x);
    // 5. LN2
    hipLaunchKernelGGL((ln_kernel<1>), dim3(TOK), dim3(128), 0, stream,
                       R, n2g, n2b, A);
    // 6. fc1 + exact GELU
    hipLaunchKernelGGL((gemm_k<3>), dim3(512 / 64, TOK / 64), dim3(256), 0, stream,
                       A, fc1_w, fc1_b, H, TOK, 512, 128, nullptr);
    // 7. fc2 + residual -> f32 out
    hipLaunchKernelGGL((gemm_k<4>), dim3(128 / 64, TOK / 64), dim3(256), 0, stream,
                       H, fc2_w, fc2_b, out, TOK, 128, 512, R);
}

// Round 3
// 489.723 us; speedup vs baseline: 2.8627x; 2.8627x over previous
//
#include <hip/hip_runtime.h>
#include <math.h>

// ---- problem constants ----
#define TOK    50176      // 2*8*56*56 tokens
#define CH     128
#define NWIN   128        // B * 64 windows
#define NTOK   392        // 8*7*7 tokens per window
#define NHEADS 4
#define QSCALE 0.17677669529663687f   // 32^-0.5
#define LNEPS  1e-3f
#define PST    424        // Vt/Ps padded row length (848 B = 53*16, bank-friendly)
#define BSTR   416        // bias table row length

typedef unsigned short u16;
typedef u16   u16x8  __attribute__((ext_vector_type(8)));
typedef short s16x8  __attribute__((ext_vector_type(8)));
typedef float f32x4  __attribute__((ext_vector_type(4)));

__device__ __forceinline__ float bf2f(u16 u) {
    return __uint_as_float(((unsigned)u) << 16);
}
__device__ __forceinline__ u16 f2bf(float f) {
    unsigned u = __float_as_uint(f);
    return (u16)((u + 0x7fffu + ((u >> 16) & 1u)) >> 16);
}

// token m in window layout -> flat token index in original layout (+3 roll)
__device__ __forceinline__ int src_index(int m) {
    int b = m / NTOK, t = m - b * NTOK;
    int batch = b >> 6, wIdx = b & 63;
    int bh = wIdx >> 3, bw = wIdx & 7;
    int d = t / 49, rem = t - d * 49;
    int h7 = rem / 7, w7 = rem - h7 * 7;
    int h = bh * 7 + h7 + 3; if (h >= 56) h -= 56;
    int w = bw * 7 + w7 + 3; if (w >= 56) w -= 56;
    return ((batch * 8 + d) * 56 + h) * 56 + w;
}

// ---- LayerNorm ----
template<int MODE>
__global__ __launch_bounds__(128) void ln_kernel(
    const float* __restrict__ xin,
    const float* __restrict__ g, const float* __restrict__ bta,
    float* __restrict__ out)
{
    int m = blockIdx.x, c = threadIdx.x;
    float v;
    if (MODE == 0) v = xin[(size_t)src_index(m) * CH + c];
    else           v = xin[(size_t)m * CH + c];
    float s1 = v, s2 = v * v;
    #pragma unroll
    for (int o = 32; o; o >>= 1) { s1 += __shfl_xor(s1, o); s2 += __shfl_xor(s2, o); }
    __shared__ float ps[2][2];
    int w = c >> 6;
    if ((c & 63) == 0) { ps[w][0] = s1; ps[w][1] = s2; }
    __syncthreads();
    s1 = ps[0][0] + ps[1][0];
    s2 = ps[0][1] + ps[1][1];
    float mean = s1 * (1.f / CH);
    float var  = s2 * (1.f / CH) - mean * mean;
    float r = rsqrtf(var + LNEPS);
    out[(size_t)m * CH + c] = (v - mean) * r * g[c] + bta[c];
}

// ---- tiled fp32 GEMM with epilogues (unchanged from r2) ----
template<int EPI>
__global__ __launch_bounds__(256) void gemm_k(
    const float* __restrict__ A, const float* __restrict__ B,
    const float* __restrict__ bias, float* __restrict__ Cout,
    int M, int Nn, int K,
    const float* __restrict__ resid)
{
    __shared__ float As[16][66];
    __shared__ float Bs[16][64];
    int tid = threadIdx.x;
    int tx = tid & 15, ty = tid >> 4;
    int m0 = blockIdx.y * 64, n0 = blockIdx.x * 64;
    float acc[4][4] = {};
    for (int k0 = 0; k0 < K; k0 += 16) {
        #pragma unroll
        for (int p = 0; p < 4; ++p) {
            int e = tid + p * 256;
            int r = e >> 4, kk = e & 15;
            As[kk][r] = A[(size_t)(m0 + r) * K + k0 + kk];
        }
        #pragma unroll
        for (int p = 0; p < 4; ++p) {
            int e = tid + p * 256;
            int kk = e >> 6, n = e & 63;
            Bs[kk][n] = B[(size_t)(k0 + kk) * Nn + n0 + n];
        }
        __syncthreads();
        #pragma unroll
        for (int kk = 0; kk < 16; ++kk) {
            float a[4], b[4];
            #pragma unroll
            for (int i = 0; i < 4; ++i) a[i] = As[kk][ty * 4 + i];
            #pragma unroll
            for (int j = 0; j < 4; ++j) b[j] = Bs[kk][tx * 4 + j];
            #pragma unroll
            for (int i = 0; i < 4; ++i)
                #pragma unroll
                for (int j = 0; j < 4; ++j)
                    acc[i][j] = fmaf(a[i], b[j], acc[i][j]);
        }
        __syncthreads();
    }
    #pragma unroll
    for (int i = 0; i < 4; ++i) {
        int m = m0 + ty * 4 + i;
        #pragma unroll
        for (int j = 0; j < 4; ++j) {
            int n = n0 + tx * 4 + j;
            float v = acc[i][j] + bias[n];
            if (EPI == 1) {
                if (n < 128) v *= QSCALE;
                Cout[(size_t)m * Nn + n] = v;
            } else if (EPI == 2) {
                int dst = src_index(m);
                Cout[(size_t)dst * CH + n] = v + resid[(size_t)dst * CH + n];
            } else if (EPI == 3) {
                Cout[(size_t)m * Nn + n] = 0.5f * v * (1.f + erff(v * 0.70710678118654752f));
            } else {
                Cout[(size_t)m * CH + n] = v + resid[(size_t)m * CH + n];
            }
        }
    }
}

// ---- bias+mask table precompute: biasT[head][wt][i][j] bf16 ----
__global__ __launch_bounds__(416) void bias_k(
    const float* __restrict__ rpb, u16* __restrict__ biasT)
{
    int i = blockIdx.x;            // 0..391
    int hw = blockIdx.y;           // head*4 + wt
    int j = threadIdx.x;           // 0..415
    int head = hw >> 2, wt = hw & 3;
    float v;
    if (j >= NTOK) v = -100.f;
    else {
        int di = i / 49, ri = i - di * 49, hi = ri / 7, wi = ri - hi * 7;
        int dj = j / 49, rj = j - dj * 49, hj = rj / 7, wj = rj - hj * 7;
        int bidx = (di - dj + 7) * 169 + (hi - hj + 6) * 13 + (wi - wj + 6);
        v = rpb[bidx * NHEADS + head];
        int bh7 = wt >> 1, bw7 = wt & 1;
        int regi = (bh7 ? (hi < 4 ? 1 : 2) : 0) * 3 + (bw7 ? (wi < 4 ? 1 : 2) : 0);
        int regj = (bh7 ? (hj < 4 ? 1 : 2) : 0) * 3 + (bw7 ? (wj < 4 ? 1 : 2) : 0);
        if (regi != regj) v -= 100.f;
    }
    biasT[((size_t)hw * NTOK + i) * BSTR + j] = f2bf(v);
}

// ---- MFMA attention: one block per (win, head), 4 waves ----
__device__ __forceinline__ f32x4 mfma16(s16x8 a, s16x8 b, f32x4 c) {
    return __builtin_amdgcn_mfma_f32_16x16x32_bf16(a, b, c, 0, 0, 0);
}

__global__ __launch_bounds__(256, 1) void attn_mfma(
    const float* __restrict__ Qb, const u16* __restrict__ biasT,
    float* __restrict__ O)
{
    extern __shared__ char smem[];
    u16 (*Kb)[40]  = (u16(*)[40])smem;                        // [400][40]  32000 B
    u16 (*Vt)[PST] = (u16(*)[PST])(smem + 32000);             // [32][424]  27136 B
    u16 (*Ps)[PST] = (u16(*)[PST])(smem + 32000 + 27136);     // [64][424]  54272 B

    int bid = blockIdx.x;
    int win = bid >> 2, head = bid & 3;
    int tid = threadIdx.x, w = tid >> 6, l = tid & 63;
    int c16 = l & 15, g4 = l >> 4;

    const size_t qbase = (size_t)win * NTOK * 384;
    // stage K [token][d] and V^T [d][token] as bf16; pad tokens 392..415 = 0
    for (int e = tid; e < 400 * 32; e += 256) {
        int j = e >> 5, d = e & 31;
        float kv = 0.f, vv = 0.f;
        if (j < NTOK) {
            kv = Qb[qbase + (size_t)j * 384 + 128 + head * 32 + d];
            vv = Qb[qbase + (size_t)j * 384 + 256 + head * 32 + d];
        }
        Kb[j][d] = f2bf(kv);
        Vt[d][j] = f2bf(vv);
    }
    for (int e = tid; e < 32 * 16; e += 256)
        Vt[e >> 4][400 + (e & 15)] = 0;
    // zero own P stripe's pad columns
    u16 (*myPs)[PST] = &Ps[w * 16];
    for (int e = l; e < 16 * 16; e += 64)
        myPs[e >> 4][400 + (e & 15)] = 0;
    __syncthreads();

    int wIdx = win & 63;
    int wt = (((wIdx >> 3) == 7) ? 2 : 0) + (((wIdx & 7) == 7) ? 1 : 0);
    const u16* bias0 = biasT + (size_t)(head * 4 + wt) * NTOK * BSTR;

    for (int t = w; t < 25; t += 4) {
        int row0 = t * 16;
        // Q A-fragment from global (f32 -> bf16), rows clamped
        int qr = row0 + c16; if (qr > NTOK - 1) qr = NTOK - 1;
        const float* qp = Qb + qbase + (size_t)qr * 384 + head * 32 + g4 * 8;
        u16x8 au;
        #pragma unroll
        for (int i = 0; i < 8; ++i) au[i] = f2bf(qp[i]);
        s16x8 afrag = __builtin_bit_cast(s16x8, au);

        // QK^T: 25 N-tiles, K=32 in one MFMA each
        f32x4 acc[25];
        #pragma unroll
        for (int nt = 0; nt < 25; ++nt) {
            s16x8 bfrag = __builtin_bit_cast(s16x8, *(const u16x8*)&Kb[nt * 16 + c16][g4 * 8]);
            f32x4 zz = {0.f, 0.f, 0.f, 0.f};
            acc[nt] = mfma16(afrag, bfrag, zz);
        }

        // bias + mask add, row max
        int rbase = row0 + g4 * 4;
        float mx[4] = {-1e30f, -1e30f, -1e30f, -1e30f};
        #pragma unroll
        for (int nt = 0; nt < 25; ++nt) {
            #pragma unroll
            for (int r = 0; r < 4; ++r) {
                int br = rbase + r; if (br > NTOK - 1) br = NTOK - 1;
                float bv = bf2f(bias0[(size_t)br * BSTR + nt * 16 + c16]);
                acc[nt][r] += bv;
                mx[r] = fmaxf(mx[r], acc[nt][r]);
            }
        }
        #pragma unroll
        for (int r = 0; r < 4; ++r)
            #pragma unroll
            for (int o = 1; o <= 8; o <<= 1)
                mx[r] = fmaxf(mx[r], __shfl_xor(mx[r], o));

        // exp, sum, write P stripe (bf16)
        float sm[4] = {0.f, 0.f, 0.f, 0.f};
        #pragma unroll
        for (int nt = 0; nt < 25; ++nt) {
            #pragma unroll
            for (int r = 0; r < 4; ++r) {
                float p = exp2f((acc[nt][r] - mx[r]) * 1.44269504f);
                sm[r] += p;
                myPs[g4 * 4 + r][nt * 16 + c16] = f2bf(p);
            }
        }
        #pragma unroll
        for (int r = 0; r < 4; ++r) {
            #pragma unroll
            for (int o = 1; o <= 8; o <<= 1)
                sm[r] += __shfl_xor(sm[r], o);
            sm[r] = 1.f / sm[r];
        }

        // PV: O(16x32) = P(16x416) * V(416x32)
        f32x4 oacc[2] = {{0.f,0.f,0.f,0.f},{0.f,0.f,0.f,0.f}};
        #pragma unroll
        for (int jb = 0; jb < 13; ++jb) {
            s16x8 pa = __builtin_bit_cast(s16x8, *(const u16x8*)&myPs[c16][jb * 32 + g4 * 8]);
            #pragma unroll
            for (int nd = 0; nd < 2; ++nd) {
                s16x8 vb = __builtin_bit_cast(s16x8, *(const u16x8*)&Vt[nd * 16 + c16][jb * 32 + g4 * 8]);
                oacc[nd] = mfma16(pa, vb, oacc[nd]);
            }
        }
        #pragma unroll
        for (int nd = 0; nd < 2; ++nd)
            #pragma unroll
            for (int r = 0; r < 4; ++r) {
                int qrow = rbase + r;
                if (qrow < NTOK)
                    O[((size_t)(win * NTOK + qrow)) * CH + head * 32 + nd * 16 + c16]
                        = oacc[nd][r] * sm[r];
            }
    }
}

#define ATTN_LDS (32000 + 27136 + 54272)

extern "C" void kernel_launch(void* const* d_in, const int* in_sizes, int n_in,
                              void* d_out, int out_size, void* d_ws, size_t ws_size,
                              hipStream_t stream) {
    const float* x      = (const float*)d_in[0];
    const float* n1g    = (const float*)d_in[1];
    const float* n1b    = (const float*)d_in[2];
    const float* qkv_w  = (const float*)d_in[3];
    const float* qkv_b  = (const float*)d_in[4];
    const float* proj_w = (const float*)d_in[5];
    const float* proj_b = (const float*)d_in[6];
    const float* rpb    = (const float*)d_in[7];
    const float* n2g    = (const float*)d_in[8];
    const float* n2b    = (const float*)d_in[9];
    const float* fc1_w  = (const float*)d_in[10];
    const float* fc1_b  = (const float*)d_in[11];
    const float* fc2_w  = (const float*)d_in[12];
    const float* fc2_b  = (const float*)d_in[13];
    float* out = (float*)d_out;

    char* ws = (char*)d_ws;
    const size_t SA = (size_t)TOK * CH * sizeof(float);
    float* A  = (float*)(ws);            // LN out; attn-phase: biasT
    float* R  = (float*)(ws + SA);       // residual
    float* Qb = (float*)(ws + 2 * SA);   // qkv
    float* O  = (float*)(ws + 5 * SA);   // attn out
    float* H  = (float*)(ws + 2 * SA);   // gelu(fc1) overlays Qb+O
    u16* biasT = (u16*)A;                // 5.2 MB inside A (dead between qkv and LN2)

    hipFuncSetAttribute(reinterpret_cast<const void*>(attn_mfma),
                        hipFuncAttributeMaxDynamicSharedMemorySize, ATTN_LDS);

    // 1. LN1 + shift + window_partition
    hipLaunchKernelGGL((ln_kernel<0>), dim3(TOK), dim3(128), 0, stream, x, n1g, n1b, A);
    // 2. qkv GEMM (+bias, q-scale)
    hipLaunchKernelGGL((gemm_k<1>), dim3(384 / 64, TOK / 64), dim3(256), 0, stream,
                       A, qkv_w, qkv_b, Qb, TOK, 384, 128, nullptr);
    // 2b. bias+mask table (A is dead now)
    hipLaunchKernelGGL(bias_k, dim3(NTOK, 16), dim3(BSTR), 0, stream, rpb, biasT);
    // 3. MFMA windowed attention
    hipLaunchKernelGGL(attn_mfma, dim3(NWIN * NHEADS), dim3(256), ATTN_LDS, stream,
                       Qb, biasT, O);
    // 4. proj GEMM + window_reverse + unshift + residual -> R
    hipLaunchKernelGGL((gemm_k<2>), dim3(128 / 64, TOK / 64), dim3(256), 0, stream,
                       O, proj_w, proj_b, R, TOK, 128, 128, x);
    // 5. LN2
    hipLaunchKernelGGL((ln_kernel<1>), dim3(TOK), dim3(128), 0, stream, R, n2g, n2b, A);
    // 6. fc1 + exact GELU
    hipLaunchKernelGGL((gemm_k<3>), dim3(512 / 64, TOK / 64), dim3(256), 0, stream,
                       A, fc1_w, fc1_b, H, TOK, 512, 128, nullptr);
    // 7. fc2 + residual -> f32 out
    hipLaunchKernelGGL((gemm_k<4>), dim3(128 / 64, TOK / 64), dim3(256), 0, stream,
                       H, fc2_w, fc2_b, out, TOK, 128, 512, R);
}

// Round 4
// 229.117 us; speedup vs baseline: 6.1189x; 2.1374x over previous
//
#include <hip/hip_runtime.h>
#include <math.h>

// ---- problem constants ----
#define TOK    50176      // 2*8*56*56 tokens
#define CH     128
#define NWIN   128        // B * 64 windows
#define NTOK   392        // 8*7*7 tokens per window
#define NHEADS 4
#define QSCALE 0.17677669529663687f   // 32^-0.5
#define LNEPS  1e-3f
#define PST    424        // Vt/Ps padded row length

typedef unsigned short u16;
typedef u16   u16x4  __attribute__((ext_vector_type(4)));
typedef u16   u16x8  __attribute__((ext_vector_type(8)));
typedef short s16x8  __attribute__((ext_vector_type(8)));
typedef float f32x4  __attribute__((ext_vector_type(4)));

__device__ __forceinline__ float bf2f(u16 u) {
    return __uint_as_float(((unsigned)u) << 16);
}
__device__ __forceinline__ u16 f2bf(float f) {
    unsigned u = __float_as_uint(f);
    return (u16)((u + 0x7fffu + ((u >> 16) & 1u)) >> 16);
}
__device__ __forceinline__ f32x4 mfma16(s16x8 a, s16x8 b, f32x4 c) {
    return __builtin_amdgcn_mfma_f32_16x16x32_bf16(a, b, c, 0, 0, 0);
}

// token m in window layout -> flat token index in original layout (+3 roll)
__device__ __forceinline__ int src_index(int m) {
    int b = m / NTOK, t = m - b * NTOK;
    int batch = b >> 6, wIdx = b & 63;
    int bh = wIdx >> 3, bw = wIdx & 7;
    int d = t / 49, rem = t - d * 49;
    int h7 = rem / 7, w7 = rem - h7 * 7;
    int h = bh * 7 + h7 + 3; if (h >= 56) h -= 56;
    int w = bw * 7 + w7 + 3; if (w >= 56) w -= 56;
    return ((batch * 8 + d) * 56 + h) * 56 + w;
}

// ---- weight transpose + f32->bf16 convert: dst[n][k] = src[k][n] * sc ----
__global__ __launch_bounds__(256) void convT(
    const float* __restrict__ src, u16* __restrict__ dst,
    int K, int N, int scaleN)
{
    __shared__ float t[32][33];
    int n0 = blockIdx.x * 32, k0 = blockIdx.y * 32;
    int tx = threadIdx.x & 31, ty = threadIdx.x >> 5;   // ty 0..7
    #pragma unroll
    for (int r = 0; r < 4; ++r)
        t[ty + r * 8][tx] = src[(size_t)(k0 + ty + r * 8) * N + n0 + tx];
    __syncthreads();
    #pragma unroll
    for (int r = 0; r < 4; ++r) {
        int n = n0 + ty + r * 8;
        float sc = (n < scaleN) ? QSCALE : 1.f;
        dst[(size_t)n * K + k0 + tx] = f2bf(t[tx][ty + r * 8] * sc);
    }
}

// ---- LayerNorm -> bf16 out ----
template<int MODE>
__global__ __launch_bounds__(128) void ln_kernel(
    const float* __restrict__ xin,
    const float* __restrict__ g, const float* __restrict__ bta,
    u16* __restrict__ out)
{
    int m = blockIdx.x, c = threadIdx.x;
    float v;
    if (MODE == 0) v = xin[(size_t)src_index(m) * CH + c];
    else           v = xin[(size_t)m * CH + c];
    float s1 = v, s2 = v * v;
    #pragma unroll
    for (int o = 32; o; o >>= 1) { s1 += __shfl_xor(s1, o); s2 += __shfl_xor(s2, o); }
    __shared__ float ps[2][2];
    int w = c >> 6;
    if ((c & 63) == 0) { ps[w][0] = s1; ps[w][1] = s2; }
    __syncthreads();
    s1 = ps[0][0] + ps[1][0];
    s2 = ps[0][1] + ps[1][1];
    float mean = s1 * (1.f / CH);
    float var  = s2 * (1.f / CH) - mean * mean;
    float r = rsqrtf(var + LNEPS);
    out[(size_t)m * CH + c] = f2bf((v - mean) * r * g[c] + bta[c]);
}

// ---- MFMA GEMM: C[M][N] = A[M][K]_bf16 * W[N][K]_bf16 + bias, epilogues ----
// EPI 1: qkv -> bf16 out (bias scaled by QSCALE for n<128; W pre-scaled)
// EPI 2: proj + residual gather/scatter -> f32 R
// EPI 3: gelu -> bf16 out
// EPI 4: fc2 + resid f32 -> f32 d_out
template<int EPI>
__global__ __launch_bounds__(256) void gemm_mfma(
    const u16* __restrict__ A, const u16* __restrict__ W,
    const float* __restrict__ bias, void* __restrict__ outp,
    int K, int Nn, const float* __restrict__ resid)
{
    __shared__ u16 As[128][32];
    __shared__ u16 Bs[128][32];
    int tid = threadIdx.x, w = tid >> 6, l = tid & 63;
    int c16 = l & 15, g4 = l >> 4;
    int m0 = blockIdx.y * 128, n0 = blockIdx.x * 128;
    int wm = w & 1, wn = w >> 1;

    f32x4 acc[4][4] = {};
    int srow = w * 32 + (l >> 2), scol = (l & 3) * 8;

    for (int k0 = 0; k0 < K; k0 += 32) {
        u16x8 a0 = *(const u16x8*)&A[(size_t)(m0 + srow) * K + k0 + scol];
        u16x8 a1 = *(const u16x8*)&A[(size_t)(m0 + srow + 16) * K + k0 + scol];
        u16x8 b0 = *(const u16x8*)&W[(size_t)(n0 + srow) * K + k0 + scol];
        u16x8 b1 = *(const u16x8*)&W[(size_t)(n0 + srow + 16) * K + k0 + scol];
        *(u16x8*)&As[srow][scol]      = a0;
        *(u16x8*)&As[srow + 16][scol] = a1;
        *(u16x8*)&Bs[srow][scol]      = b0;
        *(u16x8*)&Bs[srow + 16][scol] = b1;
        __syncthreads();

        s16x8 af[4], bf[4];
        #pragma unroll
        for (int mi = 0; mi < 4; ++mi)
            af[mi] = __builtin_bit_cast(s16x8, *(const u16x8*)&As[wm * 64 + mi * 16 + c16][g4 * 8]);
        #pragma unroll
        for (int ni = 0; ni < 4; ++ni)
            bf[ni] = __builtin_bit_cast(s16x8, *(const u16x8*)&Bs[wn * 64 + ni * 16 + c16][g4 * 8]);
        #pragma unroll
        for (int mi = 0; mi < 4; ++mi)
            #pragma unroll
            for (int ni = 0; ni < 4; ++ni)
                acc[mi][ni] = mfma16(af[mi], bf[ni], acc[mi][ni]);
        __syncthreads();
    }

    #pragma unroll
    for (int mi = 0; mi < 4; ++mi) {
        #pragma unroll
        for (int r = 0; r < 4; ++r) {
            int m = m0 + wm * 64 + mi * 16 + g4 * 4 + r;
            int dst = (EPI == 2) ? src_index(m) : m;
            #pragma unroll
            for (int ni = 0; ni < 4; ++ni) {
                int col = n0 + wn * 64 + ni * 16 + c16;
                float v = acc[mi][ni][r];
                if (EPI == 1) {
                    v += bias[col] * (col < 128 ? QSCALE : 1.f);
                    ((u16*)outp)[(size_t)m * Nn + col] = f2bf(v);
                } else if (EPI == 2) {
                    v += bias[col];
                    ((float*)outp)[(size_t)dst * CH + col] = v + resid[(size_t)dst * CH + col];
                } else if (EPI == 3) {
                    v += bias[col];
                    v = 0.5f * v * (1.f + erff(v * 0.70710678118654752f));
                    ((u16*)outp)[(size_t)m * Nn + col] = f2bf(v);
                } else {
                    v += bias[col];
                    ((float*)outp)[(size_t)m * CH + col] = v + resid[(size_t)m * CH + col];
                }
            }
        }
    }
}

// ---- bias+mask table in MFMA C-fragment layout: [hw][t][nt][lane][r] bf16 ----
__global__ __launch_bounds__(64) void bias_k(
    const float* __restrict__ rpb, u16* __restrict__ biasT2)
{
    int nt = blockIdx.x;   // 0..24 (col tile)
    int t  = blockIdx.y;   // 0..24 (row tile)
    int hw = blockIdx.z;   // head*4 + wt
    int l  = threadIdx.x;  // 0..63
    int head = hw >> 2, wt = hw & 3;
    int bh7 = wt >> 1, bw7 = wt & 1;
    int j = nt * 16 + (l & 15);
    int rb = t * 16 + (l >> 4) * 4;
    u16x4 outv;
    #pragma unroll
    for (int r = 0; r < 4; ++r) {
        int i = rb + r; if (i > NTOK - 1) i = NTOK - 1;
        float v;
        if (j >= NTOK) v = -100.f;
        else {
            int di = i / 49, ri = i - di * 49, hi = ri / 7, wi = ri - hi * 7;
            int dj = j / 49, rj = j - dj * 49, hj = rj / 7, wj = rj - hj * 7;
            int bidx = (di - dj + 7) * 169 + (hi - hj + 6) * 13 + (wi - wj + 6);
            v = rpb[bidx * NHEADS + head];
            int regi = (bh7 ? (hi < 4 ? 1 : 2) : 0) * 3 + (bw7 ? (wi < 4 ? 1 : 2) : 0);
            int regj = (bh7 ? (hj < 4 ? 1 : 2) : 0) * 3 + (bw7 ? (wj < 4 ? 1 : 2) : 0);
            if (regi != regj) v -= 100.f;
        }
        outv[r] = f2bf(v);
    }
    *(u16x4*)&biasT2[((((size_t)hw * 25 + t) * 25 + nt) << 8) + (l << 2)] = outv;
}

// ---- MFMA attention: one block per (win, head), 4 waves ----
__global__ __launch_bounds__(256, 1) void attn_mfma(
    const u16* __restrict__ Qb, const u16* __restrict__ biasT2,
    u16* __restrict__ O)
{
    extern __shared__ char smem[];
    u16 (*Kb)[40]  = (u16(*)[40])smem;                        // [400][40]  32000 B
    u16 (*Vt)[PST] = (u16(*)[PST])(smem + 32000);             // [32][424]  27136 B
    u16 (*Ps)[PST] = (u16(*)[PST])(smem + 32000 + 27136);     // [64][424]  54272 B

    int bid = blockIdx.x;
    int win = bid >> 2, head = bid & 3;
    int tid = threadIdx.x, w = tid >> 6, l = tid & 63;
    int c16 = l & 15, g4 = l >> 4;

    const size_t qbase = (size_t)win * NTOK * 384;
    // stage K rows (vector) and V transposed (scalar scatter), bf16 source
    for (int e = tid; e < 1600; e += 256) {
        int j = e >> 2, d0 = (e & 3) * 8;
        u16x8 kv = {0, 0, 0, 0, 0, 0, 0, 0};
        u16x8 vv = {0, 0, 0, 0, 0, 0, 0, 0};
        if (j < NTOK) {
            kv = *(const u16x8*)&Qb[qbase + (size_t)j * 384 + 128 + head * 32 + d0];
            vv = *(const u16x8*)&Qb[qbase + (size_t)j * 384 + 256 + head * 32 + d0];
        }
        *(u16x8*)&Kb[j][d0] = kv;
        #pragma unroll
        for (int i = 0; i < 8; ++i) Vt[d0 + i][j] = vv[i];
    }
    for (int e = tid; e < 32 * 16; e += 256)
        Vt[e >> 4][400 + (e & 15)] = 0;
    u16 (*myPs)[PST] = &Ps[w * 16];
    for (int e = l; e < 16 * 16; e += 64)
        myPs[e >> 4][400 + (e & 15)] = 0;
    __syncthreads();

    int wIdx = win & 63;
    int wt = (((wIdx >> 3) == 7) ? 2 : 0) + (((wIdx & 7) == 7) ? 1 : 0);
    const u16* bt = biasT2 + (((size_t)(head * 4 + wt) * 25) * 25 << 8) + (l << 2);

    for (int t = w; t < 25; t += 4) {
        int row0 = t * 16;
        int qr = row0 + c16; if (qr > NTOK - 1) qr = NTOK - 1;
        s16x8 afrag = __builtin_bit_cast(s16x8,
            *(const u16x8*)&Qb[qbase + (size_t)qr * 384 + head * 32 + g4 * 8]);

        f32x4 acc[25];
        #pragma unroll
        for (int nt = 0; nt < 25; ++nt) {
            s16x8 bfrag = __builtin_bit_cast(s16x8, *(const u16x8*)&Kb[nt * 16 + c16][g4 * 8]);
            f32x4 zz = {0.f, 0.f, 0.f, 0.f};
            acc[nt] = mfma16(afrag, bfrag, zz);
        }

        const u16* btt = bt + (((size_t)t * 25) << 8);
        int rbase = row0 + g4 * 4;
        float mx[4] = {-1e30f, -1e30f, -1e30f, -1e30f};
        #pragma unroll
        for (int nt = 0; nt < 25; ++nt) {
            u16x4 b4 = *(const u16x4*)(btt + ((size_t)nt << 8));
            #pragma unroll
            for (int r = 0; r < 4; ++r) {
                acc[nt][r] += bf2f(b4[r]);
                mx[r] = fmaxf(mx[r], acc[nt][r]);
            }
        }
        #pragma unroll
        for (int r = 0; r < 4; ++r)
            #pragma unroll
            for (int o = 1; o <= 8; o <<= 1)
                mx[r] = fmaxf(mx[r], __shfl_xor(mx[r], o));

        float sm[4] = {0.f, 0.f, 0.f, 0.f};
        #pragma unroll
        for (int nt = 0; nt < 25; ++nt) {
            #pragma unroll
            for (int r = 0; r < 4; ++r) {
                float p = exp2f((acc[nt][r] - mx[r]) * 1.44269504f);
                sm[r] += p;
                myPs[g4 * 4 + r][nt * 16 + c16] = f2bf(p);
            }
        }
        #pragma unroll
        for (int r = 0; r < 4; ++r) {
            #pragma unroll
            for (int o = 1; o <= 8; o <<= 1)
                sm[r] += __shfl_xor(sm[r], o);
            sm[r] = 1.f / sm[r];
        }

        f32x4 oacc[2] = {{0.f,0.f,0.f,0.f},{0.f,0.f,0.f,0.f}};
        #pragma unroll
        for (int jb = 0; jb < 13; ++jb) {
            s16x8 pa = __builtin_bit_cast(s16x8, *(const u16x8*)&myPs[c16][jb * 32 + g4 * 8]);
            #pragma unroll
            for (int nd = 0; nd < 2; ++nd) {
                s16x8 vb = __builtin_bit_cast(s16x8, *(const u16x8*)&Vt[nd * 16 + c16][jb * 32 + g4 * 8]);
                oacc[nd] = mfma16(pa, vb, oacc[nd]);
            }
        }
        #pragma unroll
        for (int nd = 0; nd < 2; ++nd)
            #pragma unroll
            for (int r = 0; r < 4; ++r) {
                int qrow = rbase + r;
                if (qrow < NTOK)
                    O[((size_t)(win * NTOK + qrow)) * CH + head * 32 + nd * 16 + c16]
                        = f2bf(oacc[nd][r] * sm[r]);
            }
    }
}

#define ATTN_LDS (32000 + 27136 + 54272)

extern "C" void kernel_launch(void* const* d_in, const int* in_sizes, int n_in,
                              void* d_out, int out_size, void* d_ws, size_t ws_size,
                              hipStream_t stream) {
    const float* x      = (const float*)d_in[0];
    const float* n1g    = (const float*)d_in[1];
    const float* n1b    = (const float*)d_in[2];
    const float* qkv_w  = (const float*)d_in[3];
    const float* qkv_b  = (const float*)d_in[4];
    const float* proj_w = (const float*)d_in[5];
    const float* proj_b = (const float*)d_in[6];
    const float* rpb    = (const float*)d_in[7];
    const float* n2g    = (const float*)d_in[8];
    const float* n2b    = (const float*)d_in[9];
    const float* fc1_w  = (const float*)d_in[10];
    const float* fc1_b  = (const float*)d_in[11];
    const float* fc2_w  = (const float*)d_in[12];
    const float* fc2_b  = (const float*)d_in[13];
    float* out = (float*)d_out;

    char* ws = (char*)d_ws;
    size_t off = 0;
    u16* A_bf  = (u16*)(ws + off);  off += (size_t)TOK * 128 * 2;   // 12.85 MB
    u16* Qb_bf = (u16*)(ws + off);  off += (size_t)TOK * 384 * 2;   // 38.5 MB
    u16* O_bf  = (u16*)(ws + off);  off += (size_t)TOK * 128 * 2;   // 12.85 MB
    float* R   = (float*)(ws + off); off += (size_t)TOK * 128 * 4;  // 25.7 MB
    u16* biasT2 = (u16*)(ws + off); off += (size_t)16 * 25 * 25 * 256 * 2; // 5.12 MB
    u16* qkvT  = (u16*)(ws + off);  off += 384 * 128 * 2;
    u16* projT = (u16*)(ws + off);  off += 128 * 128 * 2;
    u16* fc1T  = (u16*)(ws + off);  off += 512 * 128 * 2;
    u16* fc2T  = (u16*)(ws + off);  off += 128 * 512 * 2;
    u16* H_bf  = Qb_bf;  // overlays Qb+O exactly (TOK*512); both dead by fc1

    hipFuncSetAttribute(reinterpret_cast<const void*>(attn_mfma),
                        hipFuncAttributeMaxDynamicSharedMemorySize, ATTN_LDS);

    // 0. weight transposes (+bf16), QSCALE folded into Wq
    hipLaunchKernelGGL(convT, dim3(384/32, 128/32), dim3(256), 0, stream, qkv_w,  qkvT, 128, 384, 128);
    hipLaunchKernelGGL(convT, dim3(128/32, 128/32), dim3(256), 0, stream, proj_w, projT, 128, 128, 0);
    hipLaunchKernelGGL(convT, dim3(512/32, 128/32), dim3(256), 0, stream, fc1_w,  fc1T, 128, 512, 0);
    hipLaunchKernelGGL(convT, dim3(128/32, 512/32), dim3(256), 0, stream, fc2_w,  fc2T, 512, 128, 0);
    // 0b. bias+mask table in fragment layout
    hipLaunchKernelGGL(bias_k, dim3(25, 25, 16), dim3(64), 0, stream, rpb, biasT2);
    // 1. LN1 + shift + window_partition -> bf16
    hipLaunchKernelGGL((ln_kernel<0>), dim3(TOK), dim3(128), 0, stream, x, n1g, n1b, A_bf);
    // 2. qkv GEMM -> bf16
    hipLaunchKernelGGL((gemm_mfma<1>), dim3(3, TOK/128), dim3(256), 0, stream,
                       A_bf, qkvT, qkv_b, Qb_bf, 128, 384, nullptr);
    // 3. MFMA windowed attention -> bf16
    hipLaunchKernelGGL(attn_mfma, dim3(NWIN * NHEADS), dim3(256), ATTN_LDS, stream,
                       Qb_bf, biasT2, O_bf);
    // 4. proj GEMM + unshift + residual -> f32 R
    hipLaunchKernelGGL((gemm_mfma<2>), dim3(1, TOK/128), dim3(256), 0, stream,
                       O_bf, projT, proj_b, R, 128, 128, x);
    // 5. LN2 -> bf16
    hipLaunchKernelGGL((ln_kernel<1>), dim3(TOK), dim3(128), 0, stream, R, n2g, n2b, A_bf);
    // 6. fc1 + GELU -> bf16
    hipLaunchKernelGGL((gemm_mfma<3>), dim3(4, TOK/128), dim3(256), 0, stream,
                       A_bf, fc1T, fc1_b, H_bf, 128, 512, nullptr);
    // 7. fc2 + residual -> f32 out
    hipLaunchKernelGGL((gemm_mfma<4>), dim3(1, TOK/128), dim3(256), 0, stream,
                       H_bf, fc2T, fc2_b, out, 512, 128, R);
}